// Round 1
// baseline (319.324 us; speedup 1.0000x reference)
//
#include <hip/hip_runtime.h>
#include <hip/hip_bf16.h>

#define ALPHA 0.2f

constexpr int Nn = 4096;
constexpr int FIN = 256;
constexpr int FOUT = 128;

typedef __attribute__((ext_vector_type(8))) short short8;
typedef __attribute__((ext_vector_type(4))) float f32x4;

__device__ __forceinline__ unsigned short f2bf(float x) {
  unsigned int u = __float_as_uint(x);
  unsigned int r = (u + 0x7fffu + ((u >> 16) & 1u)) >> 16;
  return (unsigned short)r;
}

// Kernel 1: Wh = h @ W  (f32 compute). Emits WhT bf16 [b][i=128][n=4096],
// s1[b*N+n], s2[b*N+n].
// Grid: (B*N)/16 = 1024 blocks, 256 threads. Each block: 16 rows.
__global__ __launch_bounds__(256) void k1_wh(
    const float* __restrict__ h, const float* __restrict__ W,
    const float* __restrict__ a, unsigned short* __restrict__ whT,
    float* __restrict__ s1, float* __restrict__ s2) {
  __shared__ float hs[16][256];          // 16 KB
  __shared__ float ls1[4][8], ls2[4][8];
  __shared__ unsigned short tb[128][20]; // transpose buffer (padded rows)

  int t = threadIdx.x;
  int r0 = blockIdx.x * 16;              // global row base (b*N + n)
  int b = r0 >> 12;
  int nbase = r0 & 4095;

  // stage 16 h-rows (16 KB) coalesced
  const f32x4* hsrc = (const f32x4*)(h + (long long)r0 * FIN);
  f32x4* hdst = (f32x4*)&hs[0][0];
#pragma unroll
  for (int cg = 0; cg < 4; ++cg) hdst[cg * 256 + t] = hsrc[cg * 256 + t];
  __syncthreads();

  int c = t & 127;   // output column
  int rh = t >> 7;   // row half: rows rh*8 .. rh*8+7
  float acc[8] = {0.f, 0.f, 0.f, 0.f, 0.f, 0.f, 0.f, 0.f};

  const float* Wc = W + c;
  for (int k = 0; k < 256; k += 4) {
    float w0 = Wc[(k + 0) * 128];
    float w1 = Wc[(k + 1) * 128];
    float w2 = Wc[(k + 2) * 128];
    float w3 = Wc[(k + 3) * 128];
#pragma unroll
    for (int rr = 0; rr < 8; ++rr) {
      const f32x4 hv = *(const f32x4*)&hs[rh * 8 + rr][k];
      acc[rr] += hv.x * w0 + hv.y * w1 + hv.z * w2 + hv.w * w3;
    }
  }

  // s1/s2 partial: reduce acc[r]*a1[c] over the 128 c's (2 waves per rh)
  float a1c = a[c];
  float a2c = a[c + 128];
  int w = t >> 6;
#pragma unroll
  for (int rr = 0; rr < 8; ++rr) {
    float v1 = acc[rr] * a1c;
    float v2 = acc[rr] * a2c;
#pragma unroll
    for (int off = 32; off; off >>= 1) {
      v1 += __shfl_xor(v1, off);
      v2 += __shfl_xor(v2, off);
    }
    if ((t & 63) == 0) { ls1[w][rr] = v1; ls2[w][rr] = v2; }
  }

  // WhT via LDS transpose: tb[c][row_in_block]
#pragma unroll
  for (int rr = 0; rr < 8; ++rr) tb[c][rh * 8 + rr] = f2bf(acc[rr]);
  __syncthreads();

  if (t < 16) {
    int rr = t;
    float v = (rr < 8) ? ls1[0][rr] + ls1[1][rr] : ls1[2][rr - 8] + ls1[3][rr - 8];
    s1[r0 + rr] = v;
  } else if (t < 32) {
    int rr = t - 16;
    float v = (rr < 8) ? ls2[0][rr] + ls2[1][rr] : ls2[2][rr - 8] + ls2[3][rr - 8];
    s2[r0 + rr] = v;
  }

  // coalesced WhT store: row (b,c2), 16 ushorts
  {
    int c2 = t >> 1, half = t & 1;
    unsigned short* dst =
        whT + ((((long long)(b << 7) + c2) << 12) + nbase + half * 8);
    const unsigned short* src = &tb[c2][half * 8];
#pragma unroll
    for (int q = 0; q < 8; ++q) dst[q] = src[q];
  }
}

// Kernel 2: per (b,j) row: bitmask of adj, masked row max m_j, softmax denom.
// Grid: B*N = 16384 blocks, 256 threads (each thread 16 k's).
__global__ __launch_bounds__(256) void k2_stats(
    const int* __restrict__ adj, const float* __restrict__ s1,
    const float* __restrict__ s2, float* __restrict__ marr,
    float* __restrict__ rarr, unsigned long long* __restrict__ mask) {
  __shared__ float wred[4];
  __shared__ float wsum[4];
  int row = blockIdx.x;  // b*N + j
  int b = row >> 12;
  int t = threadIdx.x;
  float s1j = s1[row];
  const int* arow = adj + (long long)row * Nn;
  const float* s2b = s2 + (b << 12);

  float lr[16];
  unsigned int bits = 0;
  float lm = -3.0e38f;
#pragma unroll
  for (int it = 0; it < 16; ++it) {
    int k = it * 256 + t;
    int av = arow[k];
    float x = s1j + s2b[k];
    float v = fmaxf(x, 0.f) + ALPHA * fminf(x, 0.f);
    lr[it] = v;
    bool bit = av > 0;
    bits |= ((unsigned)bit) << it;
    if (bit) lm = fmaxf(lm, v);
    unsigned long long bal = __ballot(bit);
    if ((t & 63) == 0) mask[(long long)row * 64 + it * 4 + (t >> 6)] = bal;
  }
#pragma unroll
  for (int off = 32; off; off >>= 1) lm = fmaxf(lm, __shfl_xor(lm, off));
  if ((t & 63) == 0) wred[t >> 6] = lm;
  __syncthreads();
  float m = fmaxf(fmaxf(wred[0], wred[1]), fmaxf(wred[2], wred[3]));

  float ls = 0.f;
#pragma unroll
  for (int it = 0; it < 16; ++it)
    if ((bits >> it) & 1u) ls += __expf(lr[it] - m);
#pragma unroll
  for (int off = 32; off; off >>= 1) ls += __shfl_xor(ls, off);
  if ((t & 63) == 0) wsum[t >> 6] = ls;
  __syncthreads();
  if (t == 0) {
    float S = wsum[0] + wsum[1] + wsum[2] + wsum[3];
    if (S > 0.f) {
      marr[row] = m;
      rarr[row] = 1.f / S;
    } else {
      marr[row] = 0.f;
      rarr[row] = 0.f;
    }
  }
}

// Kernel 3: out[b,k,i] = elu( sum_j p[j,k] * Wh[j,i] ), p from bitmask+stats.
// D = A*B with A[k_local][j] = p (computed in regs), B[j][i] = Wh (LDS).
// Grid: B * N/64 = 256 blocks, 256 threads (4 waves; wave w: k rows w*16..+15).
__global__ __launch_bounds__(256) void k3_pv(
    const unsigned long long* __restrict__ mask,
    const unsigned short* __restrict__ whT, const float* __restrict__ s1,
    const float* __restrict__ marr, const float* __restrict__ rarr,
    const float* __restrict__ s2, float* __restrict__ out) {
  __shared__ __align__(16) unsigned short wt[128][40];  // 32 j bf16 + pad
  __shared__ unsigned long long mw[32];
  __shared__ float s1s[32], msh[32], rsh[32];

  int t = threadIdx.x;
  int blk = blockIdx.x;
  int b = blk >> 6;
  int kb = (blk & 63) << 6;  // 64-aligned k base
  int w = t >> 6, l = t & 63, g = l >> 4, r = l & 15;
  int kg = kb + w * 16 + r;  // this lane's output row (A row = lane&15)
  float s2k = s2[(b << 12) + kg];
  int kword = kb >> 6;
  int bitpos = kg & 63;

  f32x4 acc[8];
#pragma unroll
  for (int s = 0; s < 8; ++s) acc[s] = (f32x4){0.f, 0.f, 0.f, 0.f};

  for (int it = 0; it < 128; ++it) {
    int j0 = it * 32;
    __syncthreads();
    if (t < 32) {
      int jr = (b << 12) + j0 + t;
      mw[t] = mask[(long long)jr * 64 + kword];
      s1s[t] = s1[jr];
    } else if (t < 64) {
      int jr = (b << 12) + j0 + (t - 32);
      msh[t - 32] = marr[jr];
      rsh[t - 32] = rarr[jr];
    }
    {
      int i = t >> 1, part = t & 1;
      const f32x4* src =
          (const f32x4*)(whT + ((((long long)(b << 7) + i) << 12) + j0 + part * 16));
      *(f32x4*)&wt[i][part * 16] = src[0];
      *(f32x4*)&wt[i][part * 16 + 8] = src[1];
    }
    __syncthreads();

    // A fragment: 8 exps per lane (j = j0 + 8g + e, k = kg)
    short8 af;
#pragma unroll
    for (int e = 0; e < 8; ++e) {
      int jj = g * 8 + e;
      float x = s1s[jj] + s2k;
      float v = fmaxf(x, 0.f) + ALPHA * fminf(x, 0.f);
      float p = __expf(v - msh[jj]) * rsh[jj];
      p = ((mw[jj] >> bitpos) & 1ULL) ? p : 0.f;
      af[e] = (short)f2bf(p);
    }
#pragma unroll
    for (int s = 0; s < 8; ++s) {
      short8 bv = *(const short8*)&wt[s * 16 + r][g * 8];
      acc[s] = __builtin_amdgcn_mfma_f32_16x16x32_bf16(af, bv, acc[s], 0, 0, 0);
    }
  }

  // epilogue: D row = 4g+q (k), col = r (i); ELU; coalesced f32 stores
#pragma unroll
  for (int s = 0; s < 8; ++s) {
#pragma unroll
    for (int q = 0; q < 4; ++q) {
      int krow = kb + w * 16 + g * 4 + q;
      int icol = s * 16 + r;
      float x = acc[s][q];
      float y = x > 0.f ? x : expm1f(x);
      out[(((long long)(b << 12) + krow) << 7) + icol] = y;
    }
  }
}

extern "C" void kernel_launch(void* const* d_in, const int* in_sizes, int n_in,
                              void* d_out, int out_size, void* d_ws,
                              size_t ws_size, hipStream_t stream) {
  const float* h = (const float*)d_in[0];
  const int* adj = (const int*)d_in[1];
  const float* W = (const float*)d_in[2];
  const float* a = (const float*)d_in[3];
  float* out = (float*)d_out;

  char* ws = (char*)d_ws;
  unsigned short* whT = (unsigned short*)ws;                    // 4 MB
  float* s1 = (float*)(ws + (4 << 20));                         // 64 KB
  float* s2 = s1 + 16384;
  float* marr = s2 + 16384;
  float* rarr = marr + 16384;
  unsigned long long* mask =
      (unsigned long long*)(ws + (4 << 20) + (256 << 10));      // 8 MB

  hipLaunchKernelGGL(k1_wh, dim3(1024), dim3(256), 0, stream, h, W, a, whT, s1,
                     s2);
  hipLaunchKernelGGL(k2_stats, dim3(16384), dim3(256), 0, stream, adj, s1, s2,
                     marr, rarr, mask);
  hipLaunchKernelGGL(k3_pv, dim3(256), dim3(256), 0, stream, mask, whT, s1,
                     marr, rarr, s2, out);
}

// Round 2
// 165.007 us; speedup vs baseline: 1.9352x; 1.9352x over previous
//
#include <hip/hip_runtime.h>
#include <hip/hip_bf16.h>

#define ALPHA 0.2f
#define L2E 1.4426950408889634f

constexpr int Nn = 4096;
constexpr int FIN = 256;
constexpr int FOUT = 128;

typedef __attribute__((ext_vector_type(8))) short short8;
typedef __attribute__((ext_vector_type(4))) float f32x4;
typedef __attribute__((ext_vector_type(16))) float f32x16;
typedef __attribute__((ext_vector_type(4))) int int4v;

__device__ __forceinline__ unsigned short f2bf(float x) {
  unsigned int u = __float_as_uint(x);
  unsigned int r = (u + 0x7fffu + ((u >> 16) & 1u)) >> 16;
  return (unsigned short)r;
}

// ---------------------------------------------------------------------------
// Kernel 1: Wh = h @ W (f32). Emits whT bf16 [b][i=128][n=4096], s1, s2.
// (unchanged this round; LDS-bound ~40us, fix next round)
// ---------------------------------------------------------------------------
__global__ __launch_bounds__(256) void k1_wh(
    const float* __restrict__ h, const float* __restrict__ W,
    const float* __restrict__ a, unsigned short* __restrict__ whT,
    float* __restrict__ s1, float* __restrict__ s2) {
  __shared__ float hs[16][256];
  __shared__ float ls1[4][8], ls2[4][8];
  __shared__ unsigned short tb[128][20];

  int t = threadIdx.x;
  int r0 = blockIdx.x * 16;
  int b = r0 >> 12;
  int nbase = r0 & 4095;

  const f32x4* hsrc = (const f32x4*)(h + (long long)r0 * FIN);
  f32x4* hdst = (f32x4*)&hs[0][0];
#pragma unroll
  for (int cg = 0; cg < 4; ++cg) hdst[cg * 256 + t] = hsrc[cg * 256 + t];
  __syncthreads();

  int c = t & 127;
  int rh = t >> 7;
  float acc[8] = {0.f, 0.f, 0.f, 0.f, 0.f, 0.f, 0.f, 0.f};

  const float* Wc = W + c;
  for (int k = 0; k < 256; k += 4) {
    float w0 = Wc[(k + 0) * 128];
    float w1 = Wc[(k + 1) * 128];
    float w2 = Wc[(k + 2) * 128];
    float w3 = Wc[(k + 3) * 128];
#pragma unroll
    for (int rr = 0; rr < 8; ++rr) {
      const f32x4 hv = *(const f32x4*)&hs[rh * 8 + rr][k];
      acc[rr] += hv.x * w0 + hv.y * w1 + hv.z * w2 + hv.w * w3;
    }
  }

  float a1c = a[c];
  float a2c = a[c + 128];
  int w = t >> 6;
#pragma unroll
  for (int rr = 0; rr < 8; ++rr) {
    float v1 = acc[rr] * a1c;
    float v2 = acc[rr] * a2c;
#pragma unroll
    for (int off = 32; off; off >>= 1) {
      v1 += __shfl_xor(v1, off);
      v2 += __shfl_xor(v2, off);
    }
    if ((t & 63) == 0) { ls1[w][rr] = v1; ls2[w][rr] = v2; }
  }

#pragma unroll
  for (int rr = 0; rr < 8; ++rr) tb[c][rh * 8 + rr] = f2bf(acc[rr]);
  __syncthreads();

  if (t < 16) {
    int rr = t;
    float v = (rr < 8) ? ls1[0][rr] + ls1[1][rr] : ls1[2][rr - 8] + ls1[3][rr - 8];
    s1[r0 + rr] = v;
  } else if (t < 32) {
    int rr = t - 16;
    float v = (rr < 8) ? ls2[0][rr] + ls2[1][rr] : ls2[2][rr - 8] + ls2[3][rr - 8];
    s2[r0 + rr] = v;
  }

  {
    int c2 = t >> 1, half = t & 1;
    unsigned short* dst =
        whT + ((((long long)(b << 7) + c2) << 12) + nbase + half * 8);
    const unsigned short* src = &tb[c2][half * 8];
#pragma unroll
    for (int q = 0; q < 8; ++q) dst[q] = src[q];
  }
}

// ---------------------------------------------------------------------------
// Kernel 2: per (b,j): ushort bitmask of adj (k-blocked, 16/thread via int4),
// masked row max m, denom S; writes st2[row] = {s1_j, -(m*L2E + log2(S))}.
// ---------------------------------------------------------------------------
__global__ __launch_bounds__(256) void k2_stats(
    const int* __restrict__ adj, const float* __restrict__ s1,
    const float* __restrict__ s2, float2* __restrict__ st2,
    unsigned short* __restrict__ mask16) {
  __shared__ float wred[4], wsum[4];
  int row = blockIdx.x;  // b*N + j
  int b = row >> 12;
  int t = threadIdx.x;
  float s1j = s1[row];
  const int4v* arow = (const int4v*)(adj + (long long)row * Nn) + t * 4;
  const f32x4* s2v = (const f32x4*)(s2 + (b << 12)) + t * 4;

  float v[16];
  unsigned int bits = 0;
  float lm = -3.0e38f;
#pragma unroll
  for (int q = 0; q < 4; ++q) {
    int4v av = arow[q];
    f32x4 sv = s2v[q];
#pragma unroll
    for (int c = 0; c < 4; ++c) {
      int e = q * 4 + c;
      float x = s1j + sv[c];
      float vv = fmaxf(x, ALPHA * x);
      v[e] = vv;
      bool bit = av[c] > 0;
      bits |= ((unsigned)bit) << e;
      lm = bit ? fmaxf(lm, vv) : lm;
    }
  }
  mask16[(long long)row * 256 + t] = (unsigned short)bits;

#pragma unroll
  for (int off = 32; off; off >>= 1) lm = fmaxf(lm, __shfl_xor(lm, off));
  if ((t & 63) == 0) wred[t >> 6] = lm;
  __syncthreads();
  float m = fmaxf(fmaxf(wred[0], wred[1]), fmaxf(wred[2], wred[3]));

  float ls = 0.f;
#pragma unroll
  for (int e = 0; e < 16; ++e) {
    float ev = exp2f((v[e] - m) * L2E);
    ls += ((bits >> e) & 1u) ? ev : 0.f;
  }
#pragma unroll
  for (int off = 32; off; off >>= 1) ls += __shfl_xor(ls, off);
  if ((t & 63) == 0) wsum[t >> 6] = ls;
  __syncthreads();
  if (t == 0) {
    float S = wsum[0] + wsum[1] + wsum[2] + wsum[3];
    float negc = (S > 0.f) ? -(m * L2E + log2f(S)) : -1.0e30f;
    st2[row] = make_float2(s1j, negc);
  }
}

// ---------------------------------------------------------------------------
// Kernel 3: partial[jc][b][k][i] = sum_{j in chunk} p[j,k]*Wh[j,i]
// 32x32x16 MFMA; k-tile 128 (4 waves x 32k, full 128 i per wave);
// double-buffered LDS, XOR-swizzled wt (slot ^= (i>>3)&3 on 80B rows).
// ---------------------------------------------------------------------------
__global__ __launch_bounds__(256) void k3_pv(
    const unsigned short* __restrict__ whT, const float2* __restrict__ st2,
    const unsigned int* __restrict__ mask32, const float* __restrict__ s2,
    float* __restrict__ partial, int JC, int JTILE) {
  __shared__ __align__(16) unsigned short wt[2][128][40];  // 20 KB
  __shared__ float2 st[2][32];
  __shared__ unsigned int mk[2][32][4];

  int t = threadIdx.x;
  int blk = blockIdx.x;
  int kt = blk & 31;
  int bj = blk >> 5;
  int b = bj / JC, jc = bj % JC;
  int k0 = kt << 7;
  int j0base = jc * JTILE;

  int w = t >> 6, l = t & 63, hl = l >> 5, ln = l & 31;
  int klane = k0 + (w << 5) + ln;
  float s2k = s2[(b << 12) + klane];
  int aswz_r = (ln >> 3) & 3;  // read-side swizzle (independent of i-tile q)

  // staging roles
  int si = t >> 1, sh = t & 1;
  long long wbase = (((long long)(b << 7) + si) << 12);
  int aswz_w = (si >> 3) & 3;
  int slot0 = (sh << 1) ^ aswz_w, slot1 = ((sh << 1) + 1) ^ aswz_w;
  int tm = t - 64;

  f32x16 acc[4];
#pragma unroll
  for (int q = 0; q < 4; ++q)
#pragma unroll
    for (int r = 0; r < 16; ++r) acc[q][r] = 0.f;

  // prologue: stage iter 0 into buf 0
  {
    int j0 = j0base;
    const f32x4* src = (const f32x4*)(whT + wbase + j0 + sh * 16);
    f32x4 wv0 = src[0], wv1 = src[1];
    float2 stv;
    unsigned int mkv = 0;
    if (t < 32) stv = st2[(b << 12) + j0 + t];
    if ((unsigned)tm < 128u)
      mkv = mask32[(long long)((b << 12) + j0 + (tm >> 2)) * 128 + (kt << 2) +
                   (tm & 3)];
    *(f32x4*)((char*)&wt[0][si][0] + slot0 * 16) = wv0;
    *(f32x4*)((char*)&wt[0][si][0] + slot1 * 16) = wv1;
    if (t < 32) st[0][t] = stv;
    if ((unsigned)tm < 128u) mk[0][tm >> 2][tm & 3] = mkv;
  }
  __syncthreads();

  int iters = JTILE >> 5;
  for (int it = 0; it < iters; ++it) {
    int cur = it & 1;
    bool more = (it + 1) < iters;
    f32x4 wv0, wv1;
    float2 stv;
    unsigned int mkv = 0;
    if (more) {
      int j0 = j0base + (it + 1) * 32;
      const f32x4* src = (const f32x4*)(whT + wbase + j0 + sh * 16);
      wv0 = src[0];
      wv1 = src[1];
      if (t < 32) stv = st2[(b << 12) + j0 + t];
      if ((unsigned)tm < 128u)
        mkv = mask32[(long long)((b << 12) + j0 + (tm >> 2)) * 128 + (kt << 2) +
                     (tm & 3)];
    }

    // compute current buffer
#pragma unroll
    for (int js = 0; js < 2; ++js) {
      short8 af;
#pragma unroll
      for (int e = 0; e < 8; ++e) {
        int jj = js * 16 + hl * 8 + e;
        float2 sc = st[cur][jj];
        float x = sc.x + s2k;
        float vv = fmaxf(x, ALPHA * x);
        float p = exp2f(fmaf(vv, L2E, sc.y));
        unsigned int mv = mk[cur][jj][w];
        p = ((mv >> ln) & 1u) ? p : 0.f;
        __hip_bfloat16 hb = __float2bfloat16(p);
        af[e] = *(short*)&hb;
      }
      int slb = (js << 1) + hl;
#pragma unroll
      for (int q = 0; q < 4; ++q) {
        int i = q * 32 + ln;
        int sl = slb ^ aswz_r;
        short8 bv = *(const short8*)((const char*)&wt[cur][i][0] + sl * 16);
        acc[q] = __builtin_amdgcn_mfma_f32_32x32x16_bf16(af, bv, acc[q], 0, 0, 0);
      }
    }

    if (more) {
      int nb = cur ^ 1;
      *(f32x4*)((char*)&wt[nb][si][0] + slot0 * 16) = wv0;
      *(f32x4*)((char*)&wt[nb][si][0] + slot1 * 16) = wv1;
      if (t < 32) st[nb][t] = stv;
      if ((unsigned)tm < 128u) mk[nb][tm >> 2][tm & 3] = mkv;
    }
    __syncthreads();
  }

  // epilogue: D col = i_local (ln), row = (r&3)+8*(r>>2)+4*hl (+w*32)
  long long pbase =
      (long long)jc * 2097152 + (((long long)(b << 12) + k0) << 7);
#pragma unroll
  for (int q = 0; q < 4; ++q) {
    int i = q * 32 + ln;
#pragma unroll
    for (int r = 0; r < 16; ++r) {
      int kl = (r & 3) + ((r >> 2) << 3) + (hl << 2) + (w << 5);
      partial[pbase + (long long)kl * 128 + i] = acc[q][r];
    }
  }
}

// ---------------------------------------------------------------------------
// Kernel 4: out = elu(sum_jc partial[jc])
// ---------------------------------------------------------------------------
__global__ __launch_bounds__(256) void k4_reduce(
    const f32x4* __restrict__ partial, f32x4* __restrict__ out, int JC) {
  int idx = blockIdx.x * 256 + threadIdx.x;  // 512K f32x4
  f32x4 s = partial[idx];
  for (int jc = 1; jc < JC; ++jc) {
    f32x4 v = partial[(long long)jc * 524288 + idx];
    s.x += v.x;
    s.y += v.y;
    s.z += v.z;
    s.w += v.w;
  }
  f32x4 o;
  o.x = s.x > 0.f ? s.x : expm1f(s.x);
  o.y = s.y > 0.f ? s.y : expm1f(s.y);
  o.z = s.z > 0.f ? s.z : expm1f(s.z);
  o.w = s.w > 0.f ? s.w : expm1f(s.w);
  out[idx] = o;
}

extern "C" void kernel_launch(void* const* d_in, const int* in_sizes, int n_in,
                              void* d_out, int out_size, void* d_ws,
                              size_t ws_size, hipStream_t stream) {
  const float* h = (const float*)d_in[0];
  const int* adj = (const int*)d_in[1];
  const float* W = (const float*)d_in[2];
  const float* a = (const float*)d_in[3];

  char* ws = (char*)d_ws;
  unsigned short* whT = (unsigned short*)ws;                   // 4 MB
  float* s1 = (float*)(ws + (4 << 20));                        // 64 KB
  float* s2 = s1 + 16384;                                      // 64 KB
  float2* st2 = (float2*)(ws + (4 << 20) + (128 << 10));       // 128 KB
  unsigned short* mask16 = (unsigned short*)(ws + (8 << 20));  // 8 MB
  float* partial = (float*)(ws + (16 << 20));                  // JC * 8 MB

  int JC = 8;
  while (JC > 1 &&
         (size_t)(16u << 20) + (size_t)JC * (8u << 20) > ws_size)
    JC >>= 1;
  int JTILE = 4096 / JC;

  hipLaunchKernelGGL(k1_wh, dim3(1024), dim3(256), 0, stream, h, W, a, whT, s1,
                     s2);
  hipLaunchKernelGGL(k2_stats, dim3(16384), dim3(256), 0, stream, adj, s1, s2,
                     st2, mask16);
  hipLaunchKernelGGL(k3_pv, dim3(128 * JC), dim3(256), 0, stream, whT, st2,
                     (const unsigned int*)mask16, s2, partial, JC, JTILE);
  hipLaunchKernelGGL(k4_reduce, dim3(2048), dim3(256), 0, stream,
                     (const f32x4*)partial, (f32x4*)d_out, JC);
}

// Round 3
// 156.321 us; speedup vs baseline: 2.0427x; 1.0556x over previous
//
#include <hip/hip_runtime.h>
#include <hip/hip_bf16.h>

#define ALPHA 0.2f
#define L2E 1.4426950408889634f

constexpr int Nn = 4096;
constexpr int FIN = 256;
constexpr int FOUT = 128;

typedef __attribute__((ext_vector_type(8))) short short8;
typedef __attribute__((ext_vector_type(8))) unsigned short ushort8;
typedef __attribute__((ext_vector_type(4))) float f32x4;
typedef __attribute__((ext_vector_type(16))) float f32x16;
typedef __attribute__((ext_vector_type(4))) int int4v;

__device__ __forceinline__ unsigned short f2bf(float x) {
  unsigned int u = __float_as_uint(x);
  unsigned int r = (u + 0x7fffu + ((u >> 16) & 1u)) >> 16;
  return (unsigned short)r;
}

// ---------------------------------------------------------------------------
// k0: blocks 0..7: WT bf16 [i=128][k=256] from W f32 [k][i] (LDS transpose).
//     block 8: wa1[k] = sum_i W[k][i]*a[i], wa2[k] = sum_i W[k][i]*a[128+i].
// ---------------------------------------------------------------------------
__global__ __launch_bounds__(256) void k0_prep(
    const float* __restrict__ W, const float* __restrict__ a,
    unsigned short* __restrict__ WT, float* __restrict__ wa) {
  int t = threadIdx.x;
  int blk = blockIdx.x;
  if (blk < 8) {
    __shared__ float lw[32][132];
    int kc0 = blk * 32;
    // load 32 k-rows x 128 i (coalesced), 16 f32/thread
#pragma unroll
    for (int m = 0; m < 4; ++m) {
      int idx = t * 16 + m * 4;  // never straddles a row
      f32x4 v = *(const f32x4*)(W + kc0 * 128 + idx);
      int k = idx >> 7, i0 = idx & 127;
      *(f32x4*)&lw[k][i0] = v;
    }
    __syncthreads();
    int i = t >> 1, half = t & 1;
    unsigned short pk[16];
#pragma unroll
    for (int kk = 0; kk < 16; ++kk) pk[kk] = f2bf(lw[half * 16 + kk][i]);
    ushort8* dst = (ushort8*)(WT + i * 256 + kc0 + half * 16);
    dst[0] = *(ushort8*)&pk[0];
    dst[1] = *(ushort8*)&pk[8];
  } else {
    // wa: one block, thread t = k
    float acc1 = 0.f, acc2 = 0.f;
    const float* Wr = W + t * 128;
#pragma unroll
    for (int m = 0; m < 32; ++m) {
      f32x4 wv = *(const f32x4*)(Wr + m * 4);
      f32x4 a1 = *(const f32x4*)(a + m * 4);
      f32x4 a2 = *(const f32x4*)(a + 128 + m * 4);
      acc1 += wv.x * a1.x + wv.y * a1.y + wv.z * a1.z + wv.w * a1.w;
      acc2 += wv.x * a2.x + wv.y * a2.y + wv.z * a2.z + wv.w * a2.w;
    }
    wa[t] = acc1;
    wa[256 + t] = acc2;
  }
}

// ---------------------------------------------------------------------------
// k1a: exact f32 s1/s2: s1[row] = h[row,:]·wa1, s2[row] = h[row,:]·wa2.
// One wave per row, 4 rows/block, grid 4096.
// ---------------------------------------------------------------------------
__global__ __launch_bounds__(256) void k1a_scores(
    const float* __restrict__ h, const float* __restrict__ wa,
    float* __restrict__ s1, float* __restrict__ s2) {
  int t = threadIdx.x;
  int wv = t >> 6, l = t & 63;
  int row = blockIdx.x * 4 + wv;
  f32x4 hv = *(const f32x4*)(h + (long long)row * 256 + l * 4);
  f32x4 w1 = ((const f32x4*)wa)[l];
  f32x4 w2 = ((const f32x4*)wa)[64 + l];
  float v1 = hv.x * w1.x + hv.y * w1.y + hv.z * w1.z + hv.w * w1.w;
  float v2 = hv.x * w2.x + hv.y * w2.y + hv.z * w2.z + hv.w * w2.w;
#pragma unroll
  for (int off = 32; off; off >>= 1) {
    v1 += __shfl_xor(v1, off);
    v2 += __shfl_xor(v2, off);
  }
  if (l == 0) {
    s1[row] = v1;
    s2[row] = v2;
  }
}

// ---------------------------------------------------------------------------
// k1b: Wh via mfma_16x16x32_bf16; emits whT bf16 [b][i=128][n=4096].
// Block: 64 rows, 4 waves (wave w: rows w*16..+15, all 128 i). Grid 256.
// LDS: hch [64][128] bf16 swz @0 (16K), wch [128][128] bf16 swz @16K (32K),
//      tb [128][72] bf16 aliases @0 after compute.
// ---------------------------------------------------------------------------
__global__ __launch_bounds__(256) void k1b_wh(
    const float* __restrict__ h, const unsigned short* __restrict__ WT,
    unsigned short* __restrict__ whT) {
  __shared__ __align__(16) char smem[49152];
  int t = threadIdx.x;
  int w = t >> 6, l = t & 63, g = l >> 4, r = l & 15;
  int r0 = blockIdx.x * 64;
  int b = r0 >> 12, nbase = r0 & 4095;

  f32x4 acc[8];
#pragma unroll
  for (int s = 0; s < 8; ++s) acc[s] = (f32x4){0.f, 0.f, 0.f, 0.f};

  for (int kc = 0; kc < 2; ++kc) {
    __syncthreads();
    // stage h chunk: row = t>>2, 32 k each
    {
      int row = t >> 2, q4 = t & 3;
      const f32x4* src =
          (const f32x4*)(h + (long long)(r0 + row) * 256 + kc * 128 + q4 * 32);
#pragma unroll
      for (int m = 0; m < 4; ++m) {
        f32x4 v0 = src[m * 2], v1 = src[m * 2 + 1];
        unsigned int pk[4];
        pk[0] = ((unsigned)f2bf(v0.y) << 16) | f2bf(v0.x);
        pk[1] = ((unsigned)f2bf(v0.w) << 16) | f2bf(v0.z);
        pk[2] = ((unsigned)f2bf(v1.y) << 16) | f2bf(v1.x);
        pk[3] = ((unsigned)f2bf(v1.w) << 16) | f2bf(v1.z);
        int slot = q4 * 4 + m;
        *(ushort8*)(smem + row * 256 + ((slot ^ (row & 7)) << 4)) =
            *(ushort8*)pk;
      }
    }
    // stage WT chunk: i = t>>1, 64 k each
    {
      int i = t >> 1, pt = t & 1;
      const ushort8* src =
          (const ushort8*)(WT + i * 256 + kc * 128 + pt * 64);
#pragma unroll
      for (int m = 0; m < 8; ++m) {
        ushort8 v = src[m];
        int slot = pt * 8 + m;
        *(ushort8*)(smem + 16384 + i * 256 + ((slot ^ (i & 7)) << 4)) = v;
      }
    }
    __syncthreads();
#pragma unroll
    for (int kk = 0; kk < 4; ++kk) {
      int arow = w * 16 + r;
      short8 af = *(const short8*)(smem + arow * 256 +
                                   (((kk * 4 + g) ^ (arow & 7)) << 4));
#pragma unroll
      for (int s = 0; s < 8; ++s) {
        int i = s * 16 + r;
        short8 bf = *(const short8*)(smem + 16384 + i * 256 +
                                     (((kk * 4 + g) ^ (i & 7)) << 4));
        acc[s] = __builtin_amdgcn_mfma_f32_16x16x32_bf16(af, bf, acc[s], 0, 0, 0);
      }
    }
  }

  // transpose via tb (aliases smem) then coalesced whT store
  __syncthreads();
  unsigned short* tb = (unsigned short*)smem;  // [128][72]
#pragma unroll
  for (int s = 0; s < 8; ++s)
#pragma unroll
    for (int q = 0; q < 4; ++q)
      tb[(s * 16 + r) * 72 + w * 16 + 4 * g + q] = f2bf(acc[s][q]);
  __syncthreads();
  {
    int i = t >> 1, half = t & 1;
    const ushort8* src = (const ushort8*)(tb + i * 72 + half * 32);
    ushort8* dst =
        (ushort8*)(whT + (((long long)(b * 128 + i)) << 12) + nbase + half * 32);
#pragma unroll
    for (int m = 0; m < 4; ++m) dst[m] = src[m];
  }
}

// ---------------------------------------------------------------------------
// k2: per (b,j): ushort bitmask of adj, masked row max m, denom S;
// st2[row] = {s1_j, -(m*L2E + log2(S))}. Grid 16384 x 256.
// ---------------------------------------------------------------------------
__global__ __launch_bounds__(256) void k2_stats(
    const int* __restrict__ adj, const float* __restrict__ s1,
    const float* __restrict__ s2, float2* __restrict__ st2,
    unsigned short* __restrict__ mask16) {
  __shared__ float wred[4], wsum[4];
  int row = blockIdx.x;
  int b = row >> 12;
  int t = threadIdx.x;
  float s1j = s1[row];
  const int4v* arow = (const int4v*)(adj + (long long)row * Nn) + t * 4;
  const f32x4* s2v = (const f32x4*)(s2 + (b << 12)) + t * 4;

  float v[16];
  unsigned int bits = 0;
  float lm = -3.0e38f;
#pragma unroll
  for (int q = 0; q < 4; ++q) {
    int4v av = arow[q];
    f32x4 sv = s2v[q];
#pragma unroll
    for (int c = 0; c < 4; ++c) {
      int e = q * 4 + c;
      float x = s1j + sv[c];
      float vv = fmaxf(x, ALPHA * x);
      v[e] = vv;
      bool bit = av[c] > 0;
      bits |= ((unsigned)bit) << e;
      lm = bit ? fmaxf(lm, vv) : lm;
    }
  }
  mask16[(long long)row * 256 + t] = (unsigned short)bits;

#pragma unroll
  for (int off = 32; off; off >>= 1) lm = fmaxf(lm, __shfl_xor(lm, off));
  if ((t & 63) == 0) wred[t >> 6] = lm;
  __syncthreads();
  float m = fmaxf(fmaxf(wred[0], wred[1]), fmaxf(wred[2], wred[3]));

  float ls = 0.f;
#pragma unroll
  for (int e = 0; e < 16; ++e) {
    float ev = exp2f((v[e] - m) * L2E);
    ls += ((bits >> e) & 1u) ? ev : 0.f;
  }
#pragma unroll
  for (int off = 32; off; off >>= 1) ls += __shfl_xor(ls, off);
  if ((t & 63) == 0) wsum[t >> 6] = ls;
  __syncthreads();
  if (t == 0) {
    float S = wsum[0] + wsum[1] + wsum[2] + wsum[3];
    float negc = (S > 0.f) ? -(m * L2E + log2f(S)) : -1.0e30f;
    st2[row] = make_float2(s1j, negc);
  }
}

// ---------------------------------------------------------------------------
// k3: out[b,k,i] = elu( sum_j p[j,k]*Wh[j,i] ), fully fused.
// Grid 256 (b x 64 k-tiles of 64), 512 threads = 8 waves = 2 ksubs x 4 jq.
// j-chunks of 64, double-buffered swizzled wt; end: LDS tree-reduce over jq.
// ---------------------------------------------------------------------------
__global__ __launch_bounds__(512) void k3_pv(
    const unsigned short* __restrict__ whT, const float2* __restrict__ st2,
    const unsigned int* __restrict__ mask32, const float* __restrict__ s2,
    float* __restrict__ out) {
  __shared__ __align__(16) char smem[32768 + 1024 + 1024];
  unsigned int* mk = (unsigned int*)(smem + 32768);  // [2][64][2]
  float2* st = (float2*)(smem + 32768 + 1024);       // [2][64]

  int t = threadIdx.x;
  int blk = blockIdx.x;
  int b = blk >> 6, kt = blk & 63;
  int k0 = kt << 6;
  int w = t >> 6, l = t & 63, hl = l >> 5, ln = l & 31;
  int ks = w & 1, jq = w >> 1;
  int kg = k0 + ks * 32 + ln;
  float s2k = s2[(b << 12) + kg];

  // staging roles
  int i_s = t >> 2, q4 = t & 3;
  const unsigned short* wsrc0 =
      whT + (((long long)(b * 128 + i_s)) << 12) + q4 * 16;
  int sA = (q4 * 2) ^ (i_s & 7), sB = (q4 * 2 + 1) ^ (i_s & 7);
  int tm = t;          // t<128: mask stage (j=t>>1, word=t&1)
  int ts = t - 128;    // 0..63: st stage

  f32x16 acc[4];
#pragma unroll
  for (int q = 0; q < 4; ++q)
#pragma unroll
    for (int rr = 0; rr < 16; ++rr) acc[q][rr] = 0.f;

  // prologue: stage chunk 0 -> buf 0
  {
    ushort8 v0 = *(const ushort8*)(wsrc0);
    ushort8 v1 = *(const ushort8*)(wsrc0 + 8);
    *(ushort8*)(smem + i_s * 128 + (sA << 4)) = v0;
    *(ushort8*)(smem + i_s * 128 + (sB << 4)) = v1;
    if (tm < 128)
      mk[(tm >> 1) * 2 + (tm & 1)] =
          mask32[(long long)((b << 12) + (tm >> 1)) * 128 + kt * 2 + (tm & 1)];
    if ((unsigned)ts < 64u) st[ts] = st2[(b << 12) + ts];
  }
  __syncthreads();

  for (int c = 0; c < 64; ++c) {
    int cur = c & 1;
    bool more = c < 63;
    ushort8 v0, v1;
    unsigned int mkv = 0;
    float2 stv;
    if (more) {
      int j0 = (c + 1) * 64;
      v0 = *(const ushort8*)(wsrc0 + j0);
      v1 = *(const ushort8*)(wsrc0 + j0 + 8);
      if (tm < 128)
        mkv = mask32[(long long)((b << 12) + j0 + (tm >> 1)) * 128 + kt * 2 +
                     (tm & 1)];
      if ((unsigned)ts < 64u) stv = st2[(b << 12) + j0 + ts];
    }

    // compute wave's 16-j slice of current chunk
    {
      short8 af;
      unsigned int* mkc = mk + cur * 128;
      float2* stc = st + cur * 64;
#pragma unroll
      for (int e = 0; e < 8; ++e) {
        int jj = jq * 16 + hl * 8 + e;
        float2 sc = stc[jj];
        float x = sc.x + s2k;
        float vv = fmaxf(x, ALPHA * x);
        float p = exp2f(fmaf(vv, L2E, sc.y));
        p = ((mkc[jj * 2 + ks] >> ln) & 1u) ? p : 0.f;
        __hip_bfloat16 hb = __float2bfloat16(p);
        af[e] = *(short*)&hb;
      }
      char* wbase = smem + cur * 16384;
      int slot = jq * 2 + hl;
#pragma unroll
      for (int q = 0; q < 4; ++q) {
        int i = q * 32 + ln;
        short8 bv =
            *(const short8*)(wbase + i * 128 + ((slot ^ (i & 7)) << 4));
        acc[q] = __builtin_amdgcn_mfma_f32_32x32x16_bf16(af, bv, acc[q], 0, 0, 0);
      }
    }

    if (more) {
      char* nbase = smem + (cur ^ 1) * 16384;
      *(ushort8*)(nbase + i_s * 128 + (sA << 4)) = v0;
      *(ushort8*)(nbase + i_s * 128 + (sB << 4)) = v1;
      unsigned int* mkn = mk + (cur ^ 1) * 128;
      float2* stn = st + (cur ^ 1) * 64;
      if (tm < 128) mkn[(tm >> 1) * 2 + (tm & 1)] = mkv;
      if ((unsigned)ts < 64u) stn[ts] = stv;
    }
    __syncthreads();
  }

  // ---- tree-reduce over jq (zone aliases wt) ----
  float* zone = (float*)smem;
  int l7 = l & 7;
  int zi = ((jq >> 1) << 1) | ks;
  // phase 1a: q0,q1
  if (jq & 1) {
#pragma unroll
    for (int q = 0; q < 2; ++q)
#pragma unroll
      for (int r4 = 0; r4 < 4; ++r4) {
        f32x4 v = {acc[q][r4 * 4], acc[q][r4 * 4 + 1], acc[q][r4 * 4 + 2],
                   acc[q][r4 * 4 + 3]};
        *(f32x4*)&zone[zi * 2048 + l * 32 + ((((q << 2) | r4) ^ l7) << 2)] = v;
      }
  }
  __syncthreads();
  if (!(jq & 1)) {
#pragma unroll
    for (int q = 0; q < 2; ++q)
#pragma unroll
      for (int r4 = 0; r4 < 4; ++r4) {
        f32x4 v =
            *(f32x4*)&zone[zi * 2048 + l * 32 + ((((q << 2) | r4) ^ l7) << 2)];
        acc[q][r4 * 4] += v.x;
        acc[q][r4 * 4 + 1] += v.y;
        acc[q][r4 * 4 + 2] += v.z;
        acc[q][r4 * 4 + 3] += v.w;
      }
  }
  __syncthreads();
  // phase 1b: q2,q3
  if (jq & 1) {
#pragma unroll
    for (int q = 2; q < 4; ++q)
#pragma unroll
      for (int r4 = 0; r4 < 4; ++r4) {
        f32x4 v = {acc[q][r4 * 4], acc[q][r4 * 4 + 1], acc[q][r4 * 4 + 2],
                   acc[q][r4 * 4 + 3]};
        *(f32x4*)&zone[zi * 2048 + l * 32 +
                       (((((q - 2) << 2) | r4) ^ l7) << 2)] = v;
      }
  }
  __syncthreads();
  if (!(jq & 1)) {
#pragma unroll
    for (int q = 2; q < 4; ++q)
#pragma unroll
      for (int r4 = 0; r4 < 4; ++r4) {
        f32x4 v = *(f32x4*)&zone[zi * 2048 + l * 32 +
                                 (((((q - 2) << 2) | r4) ^ l7) << 2)];
        acc[q][r4 * 4] += v.x;
        acc[q][r4 * 4 + 1] += v.y;
        acc[q][r4 * 4 + 2] += v.z;
        acc[q][r4 * 4 + 3] += v.w;
      }
  }
  __syncthreads();
  // phase 2: jq2 -> jq0
  if (jq == 2) {
#pragma unroll
    for (int q = 0; q < 4; ++q)
#pragma unroll
      for (int r4 = 0; r4 < 4; ++r4) {
        f32x4 v = {acc[q][r4 * 4], acc[q][r4 * 4 + 1], acc[q][r4 * 4 + 2],
                   acc[q][r4 * 4 + 3]};
        *(f32x4*)&zone[ks * 4096 + l * 64 + ((((q << 2) | r4) ^ l7) << 2)] = v;
      }
  }
  __syncthreads();
  if (jq == 0) {
#pragma unroll
    for (int q = 0; q < 4; ++q)
#pragma unroll
      for (int r4 = 0; r4 < 4; ++r4) {
        f32x4 v = *(f32x4*)&zone[ks * 4096 + l * 64 +
                                 ((((q << 2) | r4) ^ l7) << 2)];
        acc[q][r4 * 4] += v.x;
        acc[q][r4 * 4 + 1] += v.y;
        acc[q][r4 * 4 + 2] += v.z;
        acc[q][r4 * 4 + 3] += v.w;
      }
    // epilogue: ELU + store (this wave owns k-rows of its ksub)
#pragma unroll
    for (int q = 0; q < 4; ++q) {
      int i = q * 32 + ln;
#pragma unroll
      for (int rr = 0; rr < 16; ++rr) {
        int kl = (rr & 3) + ((rr >> 2) << 3) + (hl << 2);
        int krow = k0 + ks * 32 + kl;
        float x = acc[q][rr];
        float y = x > 0.f ? x : expm1f(x);
        out[(((long long)(b << 12) + krow) << 7) + i] = y;
      }
    }
  }
}

extern "C" void kernel_launch(void* const* d_in, const int* in_sizes, int n_in,
                              void* d_out, int out_size, void* d_ws,
                              size_t ws_size, hipStream_t stream) {
  const float* h = (const float*)d_in[0];
  const int* adj = (const int*)d_in[1];
  const float* W = (const float*)d_in[2];
  const float* a = (const float*)d_in[3];
  float* out = (float*)d_out;

  char* ws = (char*)d_ws;
  unsigned short* WT = (unsigned short*)ws;                    // 64 KB
  float* wa = (float*)(ws + 65536);                            // 2 KB
  unsigned short* whT = (unsigned short*)(ws + (1 << 20));     // 4 MB
  float* s1 = (float*)(ws + (5 << 20));                        // 64 KB
  float* s2 = s1 + 16384;                                      // 64 KB
  float2* st2 = (float2*)(ws + (5 << 20) + (128 << 10));       // 128 KB
  unsigned short* mask16 = (unsigned short*)(ws + (6 << 20));  // 8 MB

  hipLaunchKernelGGL(k0_prep, dim3(9), dim3(256), 0, stream, W, a, WT, wa);
  hipLaunchKernelGGL(k1a_scores, dim3(4096), dim3(256), 0, stream, h, wa, s1,
                     s2);
  hipLaunchKernelGGL(k1b_wh, dim3(256), dim3(256), 0, stream, h, WT, whT);
  hipLaunchKernelGGL(k2_stats, dim3(16384), dim3(256), 0, stream, adj, s1, s2,
                     st2, mask16);
  hipLaunchKernelGGL(k3_pv, dim3(256), dim3(512), 0, stream, whT, st2,
                     (const unsigned int*)mask16, s2, out);
}